// Round 4
// baseline (137.863 us; speedup 1.0000x reference)
//
#include <hip/hip_runtime.h>
#include <hip/hip_bf16.h>

// NT-Xent (SimCLR) loss, MI355X gfx950.
// loss = (1/N) * sum_i [ ln(S_i - exp2(C1*d_ii)) - (2/C1)*dp_i ]
//   where d = zhat.zhat^T (unit rows), C1 = 2*log2(e),
//   S_i = sum_j exp2(C1*d_ij), dp_i = C1 * d_{i, i^B}.
// zb stores sqrt(C1)*zhat in bf16, pre-swizzled into MFMA fragment order so
// every GEMM load is a coalesced 1KB global_load_dwordx4.
// Swizzle: 16B chunk for (tile=row>>4, c, lane=quad*16+t) at uint4 index
//   (tile*4+c)*64 + lane, covering row=tile*16+t, k in [c*32+quad*8, +8).
// R4: 3 waves/SIMD occupancy (launch_bounds(256,3), 1024 blocks), ping-pong
// double-buffered B prefetch (no register copies, ~full-iter prefetch dist),
// d_out zeroing folded into nt_normalize.

#define NN 8192
#define BHALF 4096
#define DIMK 128

typedef __bf16 bf16x8 __attribute__((ext_vector_type(8)));
typedef float f32x4 __attribute__((ext_vector_type(4)));

#define C1F 2.8853900817779268f   // 2*log2(e)
#define SCALEF 1.6986436f         // sqrt(C1)

// ---------------- Kernel A: normalize, scale by sqrt(C1), swizzle ----------
__global__ __launch_bounds__(256) void nt_normalize(
    const float* __restrict__ zi, const float* __restrict__ zj,
    unsigned int* __restrict__ zb_packed, float* __restrict__ out) {
  if (blockIdx.x == 0 && threadIdx.x == 0) out[0] = 0.0f;  // runs before finalize
  int row = blockIdx.x * 4 + (threadIdx.x >> 6);
  int lane = threadIdx.x & 63;
  const float* src = (row < BHALF) ? (zi + (size_t)row * DIMK)
                                   : (zj + (size_t)(row - BHALF) * DIMK);
  float2 v = ((const float2*)src)[lane];
  float ss = v.x * v.x + v.y * v.y;
#pragma unroll
  for (int off = 32; off >= 1; off >>= 1) ss += __shfl_xor(ss, off, 64);
  float rn = rsqrtf(ss) * SCALEF;
  __hip_bfloat16 h0 = __float2bfloat16(v.x * rn);
  __hip_bfloat16 h1 = __float2bfloat16(v.y * rn);
  unsigned int packed = ((unsigned int)(*(unsigned short*)&h1) << 16) |
                        (*(unsigned short*)&h0);
  int tile = row >> 4, t = row & 15;
  int cq = lane >> 2;               // chunk index 0..15 (= c*4 + quad)
  int c = cq >> 2, quad = cq & 3;
  size_t widx = ((size_t)((tile * 4 + c) * 64 + quad * 16 + t)) * 4 + (lane & 3);
  zb_packed[widx] = packed;
}

// ---------------- Kernel B: streaming sim + exp2 accumulation --------------
// Block = 4 waves x 64 rows = 256 rows; sweeps 256 cols (16 tiles).
// Ping-pong B buffers: loads for tile ct+2 issued right after tile ct's MFMAs
// consume b0 -> prefetch distance ~ one full ping-pong half (~500 cyc).
// C/D: col=lane&15, row=quad*4+reg.
__global__ __launch_bounds__(256, 3) void nt_sim(
    const uint4* __restrict__ zbv, float* __restrict__ part) {
  const int lane = threadIdx.x & 63;
  const int wave = threadIdx.x >> 6;
  const int quad = lane >> 4;
  const int t = lane & 15;
  const int row_tile0 = blockIdx.y * 16 + wave * 4;
  const int TB0 = blockIdx.x * 16;

  bf16x8 A[4][4];  // [row-tile][K-chunk]
#pragma unroll
  for (int rt = 0; rt < 4; ++rt)
#pragma unroll
    for (int c = 0; c < 4; ++c)
      A[rt][c] = __builtin_bit_cast(
          bf16x8, zbv[(size_t)((row_tile0 + rt) * 4 + c) * 64 + lane]);

  float sum[4][4];
#pragma unroll
  for (int rt = 0; rt < 4; ++rt)
#pragma unroll
    for (int r = 0; r < 4; ++r) sum[rt][r] = 0.f;

  uint4 b0[4], b1[4];
#pragma unroll
  for (int c = 0; c < 4; ++c)
    b0[c] = zbv[(size_t)((TB0 + 0) * 4 + c) * 64 + lane];
#pragma unroll
  for (int c = 0; c < 4; ++c)
    b1[c] = zbv[(size_t)((TB0 + 1) * 4 + c) * 64 + lane];

  for (int ct = 0; ct < 16; ct += 2) {
    // ---- compute on b0 (tile TB0+ct), then refill b0 with tile ct+2 ----
    f32x4 acc[4];
#pragma unroll
    for (int rt = 0; rt < 4; ++rt) acc[rt] = (f32x4){0.f, 0.f, 0.f, 0.f};
#pragma unroll
    for (int c = 0; c < 4; ++c)
#pragma unroll
      for (int rt = 0; rt < 4; ++rt)
        acc[rt] = __builtin_amdgcn_mfma_f32_16x16x32_bf16(
            A[rt][c], __builtin_bit_cast(bf16x8, b0[c]), acc[rt], 0, 0, 0);
    // unconditional prefetch; tail reads land in dead ws padding past zb
#pragma unroll
    for (int c = 0; c < 4; ++c)
      b0[c] = zbv[(size_t)((TB0 + ct + 2) * 4 + c) * 64 + lane];
#pragma unroll
    for (int rt = 0; rt < 4; ++rt)
#pragma unroll
      for (int r = 0; r < 4; ++r)
        sum[rt][r] += __builtin_amdgcn_exp2f(acc[rt][r]);

    // ---- compute on b1 (tile TB0+ct+1), then refill b1 with tile ct+3 ----
#pragma unroll
    for (int rt = 0; rt < 4; ++rt) acc[rt] = (f32x4){0.f, 0.f, 0.f, 0.f};
#pragma unroll
    for (int c = 0; c < 4; ++c)
#pragma unroll
      for (int rt = 0; rt < 4; ++rt)
        acc[rt] = __builtin_amdgcn_mfma_f32_16x16x32_bf16(
            A[rt][c], __builtin_bit_cast(bf16x8, b1[c]), acc[rt], 0, 0, 0);
#pragma unroll
    for (int c = 0; c < 4; ++c)
      b1[c] = zbv[(size_t)((TB0 + ct + 3) * 4 + c) * 64 + lane];
#pragma unroll
    for (int rt = 0; rt < 4; ++rt)
#pragma unroll
      for (int r = 0; r < 4; ++r)
        sum[rt][r] += __builtin_amdgcn_exp2f(acc[rt][r]);
  }

  // reduce over the 16 col-lanes within each quad
#pragma unroll
  for (int off = 8; off >= 1; off >>= 1)
#pragma unroll
    for (int rt = 0; rt < 4; ++rt)
#pragma unroll
      for (int r = 0; r < 4; ++r)
        sum[rt][r] += __shfl_xor(sum[rt][r], off, 16);

  if (t == 0) {
    float* dst = part + (size_t)blockIdx.x * NN;
    int row_base = row_tile0 * 16;
#pragma unroll
    for (int rt = 0; rt < 4; ++rt)
#pragma unroll
      for (int r = 0; r < 4; ++r)
        dst[row_base + rt * 16 + quad * 4 + r] = sum[rt][r];
  }
}

// ---------------- Kernel C: finalize ----------------
__device__ __forceinline__ float bf2f(unsigned short s) {
  unsigned int u = (unsigned int)s << 16;
  return __builtin_bit_cast(float, u);
}

__global__ __launch_bounds__(256) void nt_finalize(
    const uint4* __restrict__ zbv, const float* __restrict__ part,
    float* __restrict__ out) {
  int i = blockIdx.x * 256 + threadIdx.x;
  int tile = i >> 4, t = i & 15;
  int p = i ^ BHALF;
  int tilep = p >> 4;
  float S = 0.f;
#pragma unroll
  for (int k = 0; k < 32; ++k) S += part[(size_t)k * NN + i];
  float dp = 0.f, dd = 0.f;
#pragma unroll
  for (int cq = 0; cq < 16; ++cq) {
    int c = cq >> 2, q = cq & 3;
    uint4 ua = zbv[(size_t)((tile * 4 + c) * 64 + q * 16 + t)];
    uint4 up = zbv[(size_t)((tilep * 4 + c) * 64 + q * 16 + t)];
    const unsigned short* pa = (const unsigned short*)&ua;
    const unsigned short* pp = (const unsigned short*)&up;
#pragma unroll
    for (int k = 0; k < 8; ++k) {
      float a = bf2f(pa[k]), pv = bf2f(pp[k]);
      dd = fmaf(a, a, dd);
      dp = fmaf(a, pv, dp);
    }
  }
  float diag = __builtin_amdgcn_exp2f(dd);        // exp2(C1 * d_ii)
  float v = logf(S - diag) - (2.0f / C1F) * dp;   // lse_i - pos_i
#pragma unroll
  for (int off = 32; off >= 1; off >>= 1) v += __shfl_xor(v, off, 64);
  __shared__ float wsum[4];
  if ((threadIdx.x & 63) == 0) wsum[threadIdx.x >> 6] = v;
  __syncthreads();
  if (threadIdx.x == 0)
    atomicAdd(out, (wsum[0] + wsum[1] + wsum[2] + wsum[3]) * (1.0f / (float)NN));
}

extern "C" void kernel_launch(void* const* d_in, const int* in_sizes, int n_in,
                              void* d_out, int out_size, void* d_ws,
                              size_t ws_size, hipStream_t stream) {
  const float* zi = (const float*)d_in[0];
  const float* zj = (const float*)d_in[1];

  // ws: zb swizzled bf16 (2 MiB) | 2 MiB dead padding (prefetch overread) |
  //     part[32][8192] (1 MiB)
  unsigned int* zb = (unsigned int*)d_ws;
  float* part = (float*)((char*)d_ws + (4u << 20));

  nt_normalize<<<NN / 4, 256, 0, stream>>>(zi, zj, zb, (float*)d_out);

  dim3 grid(32, 32);  // 32 col-blocks x 256 cols, 32 row-blocks x 256 rows
  nt_sim<<<grid, 256, 0, stream>>>((const uint4*)zb, part);

  nt_finalize<<<NN / 256, 256, 0, stream>>>((const uint4*)zb, part,
                                            (float*)d_out);
}

// Round 5
// 80.817 us; speedup vs baseline: 1.7059x; 1.7059x over previous
//
#include <hip/hip_runtime.h>
#include <hip/hip_bf16.h>

// NT-Xent (SimCLR) loss, MI355X gfx950.
// loss = (1/N) * sum_i [ ln(S_i - exp2(C1*d_ii)) - (2/C1)*dp_i ]
//   where d = zhat.zhat^T (unit rows), C1 = 2*log2(e),
//   S_i = sum_j exp2(C1*d_ij), dp_i = C1 * d_{i, i^B}.
// zb stores sqrt(C1)*zhat in bf16, pre-swizzled into MFMA fragment order:
// 16B chunk for (tile=row>>4, c, lane=quad*16+t) at uint4 index
//   (tile*4+c)*64 + lane, covering row=tile*16+t, k in [c*32+quad*8, +8).
// R5: block stages its whole 64KB B-span into LDS once via global_load_lds
// (width=16, wave-uniform dest + lane*16 -- swizzled layout is exactly DMA
// order), then a barrier-free compute loop reads B via ds_read_b128.
// R4 lesson: launch_bounds(256,3)+ping-pong spilled to scratch (156MB HBM
// writes) -- keep launch_bounds(256,2), minimal live registers.

#define NN 8192
#define BHALF 4096
#define DIMK 128

typedef __bf16 bf16x8 __attribute__((ext_vector_type(8)));
typedef float f32x4 __attribute__((ext_vector_type(4)));

#define C1F 2.8853900817779268f   // 2*log2(e)
#define SCALEF 1.6986436f         // sqrt(C1)

// ---------------- Kernel A: normalize, scale by sqrt(C1), swizzle ----------
__global__ __launch_bounds__(256) void nt_normalize(
    const float* __restrict__ zi, const float* __restrict__ zj,
    unsigned int* __restrict__ zb_packed, float* __restrict__ out) {
  if (blockIdx.x == 0 && threadIdx.x == 0) out[0] = 0.0f;  // runs before finalize
  int row = blockIdx.x * 4 + (threadIdx.x >> 6);
  int lane = threadIdx.x & 63;
  const float* src = (row < BHALF) ? (zi + (size_t)row * DIMK)
                                   : (zj + (size_t)(row - BHALF) * DIMK);
  float2 v = ((const float2*)src)[lane];
  float ss = v.x * v.x + v.y * v.y;
#pragma unroll
  for (int off = 32; off >= 1; off >>= 1) ss += __shfl_xor(ss, off, 64);
  float rn = rsqrtf(ss) * SCALEF;
  __hip_bfloat16 h0 = __float2bfloat16(v.x * rn);
  __hip_bfloat16 h1 = __float2bfloat16(v.y * rn);
  unsigned int packed = ((unsigned int)(*(unsigned short*)&h1) << 16) |
                        (*(unsigned short*)&h0);
  int tile = row >> 4, t = row & 15;
  int cq = lane >> 2;               // chunk index 0..15 (= c*4 + quad)
  int c = cq >> 2, quad = cq & 3;
  size_t widx = ((size_t)((tile * 4 + c) * 64 + quad * 16 + t)) * 4 + (lane & 3);
  zb_packed[widx] = packed;
}

// ---------------- Kernel B: streaming sim + exp2 accumulation --------------
// Block = 4 waves x 64 rows = 256 rows; 256 cols (16 tiles) staged in LDS.
// C/D: col=lane&15, row=quad*4+reg.
__global__ __launch_bounds__(256, 2) void nt_sim(
    const uint4* __restrict__ zbv, float* __restrict__ part) {
  __shared__ uint4 ldsb[4096];  // 64 KiB: B-span for this block's 256 cols

  const int lane = threadIdx.x & 63;
  const int wave = threadIdx.x >> 6;
  const int quad = lane >> 4;
  const int t = lane & 15;
  const int row_tile0 = blockIdx.y * 16 + wave * 4;

  // ---- async-stage the 64KB B-span: 64 chunks of 1KB, 16 instrs/wave ----
  // global src for chunk k: zb byte offset blockIdx.x*65536 + k*1024 + lane*16
  // LDS dest (wave-uniform): ldsb + k*1024; HW adds lane*16.
  {
    const char* gsrc = (const char*)zbv + (size_t)blockIdx.x * 65536;
#pragma unroll
    for (int k = 0; k < 16; ++k) {
      int chunk = k * 4 + wave;
      __builtin_amdgcn_global_load_lds(
          (const __attribute__((address_space(1))) unsigned int*)(
              gsrc + chunk * 1024 + lane * 16),
          (__attribute__((address_space(3))) unsigned int*)(
              (char*)ldsb + chunk * 1024),
          16, 0, 0);
    }
  }

  // ---- A fragments (persistent registers), overlaps with DMA ----
  bf16x8 A[4][4];  // [row-tile][K-chunk]
#pragma unroll
  for (int rt = 0; rt < 4; ++rt)
#pragma unroll
    for (int c = 0; c < 4; ++c)
      A[rt][c] = __builtin_bit_cast(
          bf16x8, zbv[(size_t)((row_tile0 + rt) * 4 + c) * 64 + lane]);

  float sum[4][4];
#pragma unroll
  for (int rt = 0; rt < 4; ++rt)
#pragma unroll
    for (int r = 0; r < 4; ++r) sum[rt][r] = 0.f;

  __syncthreads();  // DMA drain (vmcnt(0)) + join; only barrier in kernel

  // ---- barrier-free compute loop: 16 col-tiles from LDS ----
#pragma unroll 2
  for (int ct = 0; ct < 16; ++ct) {
    f32x4 acc[4];
#pragma unroll
    for (int rt = 0; rt < 4; ++rt) acc[rt] = (f32x4){0.f, 0.f, 0.f, 0.f};
#pragma unroll
    for (int c = 0; c < 4; ++c) {
      bf16x8 bv = __builtin_bit_cast(bf16x8, ldsb[(ct * 4 + c) * 64 + lane]);
#pragma unroll
      for (int rt = 0; rt < 4; ++rt)
        acc[rt] = __builtin_amdgcn_mfma_f32_16x16x32_bf16(A[rt][c], bv,
                                                          acc[rt], 0, 0, 0);
    }
#pragma unroll
    for (int rt = 0; rt < 4; ++rt)
#pragma unroll
      for (int r = 0; r < 4; ++r)
        sum[rt][r] += __builtin_amdgcn_exp2f(acc[rt][r]);
  }

  // reduce over the 16 col-lanes within each quad
#pragma unroll
  for (int off = 8; off >= 1; off >>= 1)
#pragma unroll
    for (int rt = 0; rt < 4; ++rt)
#pragma unroll
      for (int r = 0; r < 4; ++r)
        sum[rt][r] += __shfl_xor(sum[rt][r], off, 16);

  if (t == 0) {
    float* dst = part + (size_t)blockIdx.x * NN;
    int row_base = row_tile0 * 16;
#pragma unroll
    for (int rt = 0; rt < 4; ++rt)
#pragma unroll
      for (int r = 0; r < 4; ++r)
        dst[row_base + rt * 16 + quad * 4 + r] = sum[rt][r];
  }
}

// ---------------- Kernel C: finalize ----------------
__device__ __forceinline__ float bf2f(unsigned short s) {
  unsigned int u = (unsigned int)s << 16;
  return __builtin_bit_cast(float, u);
}

__global__ __launch_bounds__(256) void nt_finalize(
    const uint4* __restrict__ zbv, const float* __restrict__ part,
    float* __restrict__ out) {
  int i = blockIdx.x * 256 + threadIdx.x;
  int tile = i >> 4, t = i & 15;
  int p = i ^ BHALF;
  int tilep = p >> 4;
  float S = 0.f;
#pragma unroll
  for (int k = 0; k < 32; ++k) S += part[(size_t)k * NN + i];
  float dp = 0.f, dd = 0.f;
#pragma unroll
  for (int cq = 0; cq < 16; ++cq) {
    int c = cq >> 2, q = cq & 3;
    uint4 ua = zbv[(size_t)((tile * 4 + c) * 64 + q * 16 + t)];
    uint4 up = zbv[(size_t)((tilep * 4 + c) * 64 + q * 16 + t)];
    const unsigned short* pa = (const unsigned short*)&ua;
    const unsigned short* pp = (const unsigned short*)&up;
#pragma unroll
    for (int k = 0; k < 8; ++k) {
      float a = bf2f(pa[k]), pv = bf2f(pp[k]);
      dd = fmaf(a, a, dd);
      dp = fmaf(a, pv, dp);
    }
  }
  float diag = __builtin_amdgcn_exp2f(dd);        // exp2(C1 * d_ii)
  float v = logf(S - diag) - (2.0f / C1F) * dp;   // lse_i - pos_i
#pragma unroll
  for (int off = 32; off >= 1; off >>= 1) v += __shfl_xor(v, off, 64);
  __shared__ float wsum[4];
  if ((threadIdx.x & 63) == 0) wsum[threadIdx.x >> 6] = v;
  __syncthreads();
  if (threadIdx.x == 0)
    atomicAdd(out, (wsum[0] + wsum[1] + wsum[2] + wsum[3]) * (1.0f / (float)NN));
}

extern "C" void kernel_launch(void* const* d_in, const int* in_sizes, int n_in,
                              void* d_out, int out_size, void* d_ws,
                              size_t ws_size, hipStream_t stream) {
  const float* zi = (const float*)d_in[0];
  const float* zj = (const float*)d_in[1];

  // ws: zb swizzled bf16 (2 MiB) | part[32][8192] (1 MiB)
  unsigned int* zb = (unsigned int*)d_ws;
  float* part = (float*)((char*)d_ws + (2u << 20));

  nt_normalize<<<NN / 4, 256, 0, stream>>>(zi, zj, zb, (float*)d_out);

  dim3 grid(32, 32);  // 32 col-blocks x 256 cols, 32 row-blocks x 256 rows
  nt_sim<<<grid, 256, 0, stream>>>((const uint4*)zb, part);

  nt_finalize<<<NN / 256, 256, 0, stream>>>((const uint4*)zb, part,
                                            (float*)d_out);
}